// Round 7
// baseline (1505.717 us; speedup 1.0000x reference)
//
#include <hip/hip_runtime.h>

#define TLEN 512
#define FIN 16

__device__ __forceinline__ float sigm(float x) { return 1.0f / (1.0f + __expf(-x)); }
__device__ __forceinline__ float tanh_f(float x) {
  x = fminf(fmaxf(x, -15.0f), 15.0f);
  float e = __expf(2.0f * x);
  return (e - 1.0f) / (e + 1.0f);
}

// Symmetric pair-finish for GRU: lanes (2g,2g+1) hold (z,r) gate sums; both
// compute the identical update via shfl_xor (no divergence, no barrier).
__device__ __forceinline__ float gru_fin(float own_main, float own_xh, float own_hhp,
                                         int role, float hold) {
  const float oth_main = __shfl_xor(own_main, 1);
  const float xh  = own_xh  + __shfl_xor(own_xh, 1);
  const float hhp = own_hhp + __shfl_xor(own_hhp, 1);
  const float sz = role ? oth_main : own_main;
  const float sr = role ? own_main : oth_main;
  const float z = sigm(sz);
  const float r = sigm(sr);
  const float hh = tanh_f(xh + r * hhp);
  return z * hold + (1.f - z) * hh;
}

// R7: DATAFLOW pipeline — zero s_barrier in the recurrence. Waves self-pace
// with LDS progress flags (release = s_waitcnt lgkmcnt(0) + flag store;
// acquire = volatile spin + compiler barrier). 8-deep h rings; every-4-step
// backpressure checks. Roles (2 batches/block):
//   w0: L0 units 0-31          (needs F1 >= t-1)
//   w1: L0 units 32-63 + flush (needs F0 >= t-1; flush needs F3)
//   w2: L1                     (needs F0,F1 >= t)
//   w3: L2 + FULL L3           (needs F2 >= t; h2,h3 are w3-internal rings)
// One float W[192] per thread (R5 lesson: role arrays share one declaration).
__global__ __launch_bounds__(256, 1)
void rnn_flow(const float* __restrict__ x, const float* __restrict__ emb,
              const float* __restrict__ k0, const float* __restrict__ r0,
              const float* __restrict__ bi0, const float* __restrict__ bh0,
              const float* __restrict__ k1, const float* __restrict__ r1,
              const float* __restrict__ bi1, const float* __restrict__ bh1,
              const float* __restrict__ k2, const float* __restrict__ r2,
              const float* __restrict__ bi2, const float* __restrict__ bh2,
              const float* __restrict__ k3, const float* __restrict__ r3,
              const float* __restrict__ bi3, const float* __restrict__ bh3,
              const float* __restrict__ w1m, const float* __restrict__ b1,
              const float* __restrict__ w2m, const float* __restrict__ b2,
              const float* __restrict__ vv, const float* __restrict__ bv,
              const float* __restrict__ wd, const float* __restrict__ bd,
              float* __restrict__ out, float* __restrict__ obuf)
{
  __shared__ __align__(16) float s_xin[TLEN][20][2];   // 80 KB  [t][row][batch]
  __shared__ __align__(16) float s_h0[8][64][2];       // 4 KB ring
  __shared__ __align__(16) float s_h1[8][32][2];       // 2 KB
  __shared__ __align__(16) float s_h2[8][32][2];       // 2 KB (w3-internal)
  __shared__ __align__(16) float s_h3[8][32][2];       // 2 KB (w3-internal)
  __shared__ __align__(16) float s_fl[4][16][2][32];   // 16 KB h3 flush ring
  __shared__ int s_flag[8];                            // F0,F1,F2,F3,Ffl
  // epilogue
  __shared__ __align__(16) float e_w1[1024];
  __shared__ __align__(16) float e_sc[1024];
  __shared__ float e_hw2[64], e_b1[32], e_v[32], e_ctx[64];

  const int tid  = threadIdx.x;
  const int wid  = tid >> 6;
  const int lane = tid & 63;
  const int g    = lane >> 1;
  const int role = lane & 1;
  const int bb0  = blockIdx.x * 2;

#define WAITGE(idx, val) do { volatile int* _f = &s_flag[idx];                 \
    while (*_f < (val)) {} asm volatile("" ::: "memory"); } while (0)
#define WAITGE2(i0, i1, val) do { volatile int* _a = &s_flag[i0];              \
    volatile int* _b = &s_flag[i1];                                            \
    while (*_a < (val) || *_b < (val)) {} asm volatile("" ::: "memory"); } while (0)
#define PUBLISH(idx, val) do { asm volatile("s_waitcnt lgkmcnt(0)" ::: "memory"); \
    if (lane == 0) { *(volatile int*)&s_flag[idx] = (val); } } while (0)

  float W[192];
  float bm = 0.f, bxh = 0.f, bhh = 0.f;
  float cbm = 0.f, cbxh = 0.f, cbhh = 0.f;

  // ---------------- weight loading (registers, shared W[192]) ----------
  if (wid <= 1) {                      // L0: unit u = wid*32+g, col cm
    const int u  = wid * 32 + g;
    const int cm = role ? 64 + u : u;
    #pragma unroll
    for (int j = 0; j < 19; ++j) W[j] = k0[j*192 + cm];
    W[19] = 0.f;
    #pragma unroll
    for (int j = 0; j < 64; ++j) W[20+j] = r0[j*192 + cm];
    #pragma unroll
    for (int jj = 0; jj < 10; ++jj) {
      const int row = role*10 + jj;
      W[84+jj] = (row < 19) ? k0[row*192 + 128 + u] : 0.f;
    }
    #pragma unroll
    for (int jj = 0; jj < 32; ++jj) W[94+jj] = r0[(role*32+jj)*192 + 128 + u];
    bm  = bi0[cm] + bh0[cm];
    bxh = role ? 0.f : bi0[128+u];
    bhh = role ? bh0[128+u] : 0.f;
  } else if (wid == 2) {               // L1
    const int cm = role ? 32 + g : g;
    #pragma unroll
    for (int j = 0; j < 64; ++j) W[j] = k1[j*96 + cm];
    #pragma unroll
    for (int j = 0; j < 32; ++j) W[64+j] = r1[j*96 + cm];
    #pragma unroll
    for (int jj = 0; jj < 32; ++jj) W[96+jj]  = k1[(role*32+jj)*96 + 64 + g];
    #pragma unroll
    for (int jj = 0; jj < 16; ++jj) W[128+jj] = r1[(role*16+jj)*96 + 64 + g];
    bm  = bi1[cm] + bh1[cm];
    bxh = role ? 0.f : bi1[64+g];
    bhh = role ? bh1[64+g] : 0.f;
  } else {                             // L2 + full L3
    const int cm = role ? 32 + g : g;
    #pragma unroll
    for (int j = 0; j < 32; ++j) { W[j] = k2[j*96 + cm]; W[32+j] = r2[j*96 + cm]; }
    #pragma unroll
    for (int jj = 0; jj < 16; ++jj) {
      W[64+jj] = k2[(role*16+jj)*96 + 64 + g];
      W[80+jj] = r2[(role*16+jj)*96 + 64 + g];
    }
    #pragma unroll
    for (int j = 0; j < 32; ++j) { W[96+j] = k3[j*96 + cm]; W[128+j] = r3[j*96 + cm]; }
    #pragma unroll
    for (int jj = 0; jj < 16; ++jj) {
      W[160+jj] = k3[(role*16+jj)*96 + 64 + g];
      W[176+jj] = r3[(role*16+jj)*96 + 64 + g];
    }
    bm  = bi2[cm] + bh2[cm];
    bxh = role ? 0.f : bi2[64+g];
    bhh = role ? bh2[64+g] : 0.f;
    cbm  = bi3[cm] + bh3[cm];
    cbxh = bi3[64+g];
    cbhh = bh3[64+g];
  }

  // ---------------- zero rings + flags ----------------
  for (int q = tid; q < 1024; q += 256) ((float*)s_h0)[q] = 0.f;
  for (int q = tid; q < 512; q += 256) {
    ((float*)s_h1)[q] = 0.f; ((float*)s_h2)[q] = 0.f; ((float*)s_h3)[q] = 0.f;
  }
  if (tid < 8) s_flag[tid] = (tid == 4) ? 0 : -1;

  // ---------------- stage full input into LDS ----------------
  for (int r = tid; r < 2*TLEN; r += 256) {
    const int b2 = r & 1, t2 = r >> 1;
    const float* xr = &x[((size_t)(bb0 + b2) * TLEN + t2) * FIN];
    const float4 x0 = *(const float4*)(xr);
    const float4 x1 = *(const float4*)(xr + 4);
    const float4 x2 = *(const float4*)(xr + 8);
    const float4 x3 = *(const float4*)(xr + 12);
    float v[20];
    v[0]=x0.x; v[1]=x0.z; v[2]=x0.w;
    v[3]=x1.x; v[4]=x1.y; v[5]=x1.z; v[6]=x1.w;
    v[7]=x2.x; v[8]=x2.y; v[9]=x2.z; v[10]=x2.w;
    v[11]=x3.x; v[12]=x3.y; v[13]=x3.z; v[14]=x3.w;
    const int id = (int)x0.y;
    const float4 e4 = *(const float4*)&emb[id*4];
    v[15]=e4.x; v[16]=e4.y; v[17]=e4.z; v[18]=e4.w; v[19]=0.f;
    #pragma unroll
    for (int j = 0; j < 20; ++j) s_xin[t2][j][b2] = v[j];
  }
  __syncthreads();                      // the ONLY pre-epilogue barrier

  // w1's chunk flush (16 steps x 2 batches x 32 units from 4-chunk ring)
  auto flush = [&](int c) {
    const int par = c & 3;
    #pragma unroll
    for (int it = 0; it < 4; ++it) {
      const int f4 = it*64 + lane;
      const int u4 = f4 & 7, row = f4 >> 3;
      const int dt = row >> 1, b2 = row & 1;
      const float4 vq = *(const float4*)&s_fl[par][dt][b2][u4*4];
      *(float4*)&obuf[(((size_t)(bb0+b2)*TLEN) + c*16 + dt)*32 + u4*4] = vq;
    }
  };

  // ================= self-paced wave loops =================
  if (wid <= 1) {
    // ---------- w0 / w1 : L0 ----------
    const int u = wid*32 + g;
    const int FWD = wid ^ 1;            // partner flag
    float holdA = 0.f, holdB = 0.f;
    for (int t = 0; t < TLEN; ++t) {
      if ((t & 3) == 0) WAITGE(2, t - 4);          // backpressure: w2
      WAITGE(FWD, t - 1);                          // partner half of h0[t-1]
      const int sl = t & 7, slp = (t - 1) & 7;
      float a0A = bm, a0B = bm, a1A = 0.f, a1B = 0.f;
      #pragma unroll
      for (int j = 0; j < 20; j += 2) {
        const float4 q = *(const float4*)&s_xin[t][j][0];
        a0A += W[j]*q.x;   a0B += W[j]*q.y;
        a1A += W[j+1]*q.z; a1B += W[j+1]*q.w;
      }
      #pragma unroll
      for (int j = 0; j < 64; j += 2) {
        const float4 q = *(const float4*)&s_h0[slp][j][0];
        a0A += W[20+j]*q.x; a0B += W[20+j]*q.y;
        a1A += W[21+j]*q.z; a1B += W[21+j]*q.w;
      }
      float xqA = bxh, xqB = bxh;
      #pragma unroll
      for (int jj = 0; jj < 10; ++jj) {
        const float2 d = *(const float2*)&s_xin[t][role*10+jj][0];
        xqA += W[84+jj]*d.x; xqB += W[84+jj]*d.y;
      }
      float p0A = bhh, p0B = bhh, p1A = 0.f, p1B = 0.f;
      #pragma unroll
      for (int jj = 0; jj < 32; jj += 2) {
        const float4 q = *(const float4*)&s_h0[slp][role*32+jj][0];
        p0A += W[94+jj]*q.x; p0B += W[94+jj]*q.y;
        p1A += W[95+jj]*q.z; p1B += W[95+jj]*q.w;
      }
      const float hnA = gru_fin(a0A+a1A, xqA, p0A+p1A, role, holdA);
      const float hnB = gru_fin(a0B+a1B, xqB, p0B+p1B, role, holdB);
      holdA = hnA; holdB = hnB;
      if (!role) { s_h0[sl][u][0] = hnA; s_h0[sl][u][1] = hnB; }
      PUBLISH(wid, t);
      if (wid == 1 && t >= 20 && ((t - 20) & 15) == 0) {   // flush chunk
        const int c = (t - 20) >> 4;
        WAITGE(3, 16*c + 16);
        flush(c);
        PUBLISH(4, c + 1);
      }
    }
    if (wid == 1) {                     // tail flush (chunk 31)
      WAITGE(3, TLEN);
      flush(31);
      PUBLISH(4, 32);
    }
  } else if (wid == 2) {
    // ---------- w2 : L1 ----------
    float holdA = 0.f, holdB = 0.f;
    for (int t = 0; t < TLEN; ++t) {
      if ((t & 3) == 0) WAITGE(3, t - 4);          // backpressure: w3
      WAITGE2(0, 1, t);                            // h0[t] complete
      const int sl = t & 7, slp = (t - 1) & 7;
      float a0A = bm, a0B = bm, a1A = 0.f, a1B = 0.f;
      #pragma unroll
      for (int j = 0; j < 64; j += 2) {
        const float4 q = *(const float4*)&s_h0[sl][j][0];
        a0A += W[j]*q.x;   a0B += W[j]*q.y;
        a1A += W[j+1]*q.z; a1B += W[j+1]*q.w;
      }
      #pragma unroll
      for (int j = 0; j < 32; j += 2) {
        const float4 q = *(const float4*)&s_h1[slp][j][0];
        a0A += W[64+j]*q.x; a0B += W[64+j]*q.y;
        a1A += W[65+j]*q.z; a1B += W[65+j]*q.w;
      }
      float x0A = bxh, x0B = bxh, x1A = 0.f, x1B = 0.f;
      #pragma unroll
      for (int jj = 0; jj < 32; jj += 2) {
        const float4 q = *(const float4*)&s_h0[sl][role*32+jj][0];
        x0A += W[96+jj]*q.x; x0B += W[96+jj]*q.y;
        x1A += W[97+jj]*q.z; x1B += W[97+jj]*q.w;
      }
      float p0A = bhh, p0B = bhh, p1A = 0.f, p1B = 0.f;
      #pragma unroll
      for (int jj = 0; jj < 16; jj += 2) {
        const float4 q = *(const float4*)&s_h1[slp][role*16+jj][0];
        p0A += W[128+jj]*q.x; p0B += W[128+jj]*q.y;
        p1A += W[129+jj]*q.z; p1B += W[129+jj]*q.w;
      }
      const float hnA = gru_fin(a0A+a1A, x0A+x1A, p0A+p1A, role, holdA);
      const float hnB = gru_fin(a0B+a1B, x0B+x1B, p0B+p1B, role, holdB);
      holdA = hnA; holdB = hnB;
      if (!role) { s_h1[sl][g][0] = hnA; s_h1[sl][g][1] = hnB; }
      PUBLISH(2, t);
    }
  } else {
    // ---------- w3 : L2 + full L3 ----------
    float hold2A = 0.f, hold2B = 0.f, hold3A = 0.f, hold3B = 0.f;
    for (int j = 0; j <= TLEN; ++j) {
      if ((j & 15) == 0) WAITGE(4, (j >> 4) - 3);  // backpressure: flush ring
      if (j < TLEN) {
        WAITGE(2, j);                              // h1[j]
        const int sl = j & 7, slp = (j - 1) & 7;
        float a0A = bm, a0B = bm, a1A = 0.f, a1B = 0.f;
        #pragma unroll
        for (int jq = 0; jq < 32; jq += 2) {
          const float4 q = *(const float4*)&s_h1[sl][jq][0];
          a0A += W[jq]*q.x;   a0B += W[jq]*q.y;
          a1A += W[jq+1]*q.z; a1B += W[jq+1]*q.w;
        }
        #pragma unroll
        for (int jq = 0; jq < 32; jq += 2) {
          const float4 q = *(const float4*)&s_h2[slp][jq][0];
          a0A += W[32+jq]*q.x; a0B += W[32+jq]*q.y;
          a1A += W[33+jq]*q.z; a1B += W[33+jq]*q.w;
        }
        float x0A = bxh, x0B = bxh, x1A = 0.f, x1B = 0.f;
        #pragma unroll
        for (int jj = 0; jj < 16; jj += 2) {
          const float4 q = *(const float4*)&s_h1[sl][role*16+jj][0];
          x0A += W[64+jj]*q.x; x0B += W[64+jj]*q.y;
          x1A += W[65+jj]*q.z; x1B += W[65+jj]*q.w;
        }
        float p0A = bhh, p0B = bhh, p1A = 0.f, p1B = 0.f;
        #pragma unroll
        for (int jj = 0; jj < 16; jj += 2) {
          const float4 q = *(const float4*)&s_h2[slp][role*16+jj][0];
          p0A += W[80+jj]*q.x; p0B += W[80+jj]*q.y;
          p1A += W[81+jj]*q.z; p1B += W[81+jj]*q.w;
        }
        const float hnA = gru_fin(a0A+a1A, x0A+x1A, p0A+p1A, role, hold2A);
        const float hnB = gru_fin(a0B+a1B, x0B+x1B, p0B+p1B, role, hold2B);
        hold2A = hnA; hold2B = hnB;
        if (!role) { s_h2[sl][g][0] = hnA; s_h2[sl][g][1] = hnB; }
      }
      if (j >= 1) {                                // L3 for t3 = j-1
        const int t3 = j - 1;
        const int s3 = t3 & 7, s3p = (t3 - 1) & 7;
        float q0A=0.f,q0B=0.f,q1A=0.f,q1B=0.f;
        #pragma unroll
        for (int jq = 0; jq < 32; jq += 2) {       // k3 . h2[t3]
          const float4 q = *(const float4*)&s_h2[s3][jq][0];
          q0A += W[96+jq]*q.x; q0B += W[96+jq]*q.y;
          q1A += W[97+jq]*q.z; q1B += W[97+jq]*q.w;
        }
        #pragma unroll
        for (int jq = 0; jq < 32; jq += 2) {       // r3 . h3[t3-1]
          const float4 q = *(const float4*)&s_h3[s3p][jq][0];
          q0A += W[128+jq]*q.x; q0B += W[128+jq]*q.y;
          q1A += W[129+jq]*q.z; q1B += W[129+jq]*q.w;
        }
        float xh0A=0.f,xh0B=0.f,xh1A=0.f,xh1B=0.f;
        #pragma unroll
        for (int jj = 0; jj < 16; jj += 2) {       // k3 hh-part of h2[t3]
          const float4 q = *(const float4*)&s_h2[s3][role*16+jj][0];
          xh0A += W[160+jj]*q.x; xh0B += W[160+jj]*q.y;
          xh1A += W[161+jj]*q.z; xh1B += W[161+jj]*q.w;
        }
        float ph0A=0.f,ph0B=0.f,ph1A=0.f,ph1B=0.f;
        #pragma unroll
        for (int jj = 0; jj < 16; jj += 2) {       // r3 hh-part of h3[t3-1]
          const float4 q = *(const float4*)&s_h3[s3p][role*16+jj][0];
          ph0A += W[176+jj]*q.x; ph0B += W[176+jj]*q.y;
          ph1A += W[177+jj]*q.z; ph1B += W[177+jj]*q.w;
        }
        const float mainA = q0A + q1A + cbm;
        const float mainB = q0B + q1B + cbm;
        const float xhAo = xh0A + xh1A, xhBo = xh0B + xh1B;
        const float phAo = ph0A + ph1A, phBo = ph0B + ph1B;
        const float othA = __shfl_xor(mainA, 1);
        const float othB = __shfl_xor(mainB, 1);
        const float xhA = xhAo + __shfl_xor(xhAo, 1) + cbxh;
        const float xhB = xhBo + __shfl_xor(xhBo, 1) + cbxh;
        const float hhpA = phAo + __shfl_xor(phAo, 1) + cbhh;
        const float hhpB = phBo + __shfl_xor(phBo, 1) + cbhh;
        const float szA = role ? othA : mainA;
        const float srA = role ? mainA : othA;
        const float szB = role ? othB : mainB;
        const float srB = role ? mainB : othB;
        const float zA = sigm(szA), rA = sigm(srA);
        const float zB = sigm(szB), rB = sigm(srB);
        const float hhA = tanh_f(xhA + rA*hhpA);
        const float hhB = tanh_f(xhB + rB*hhpB);
        const float hnA = zA*hold3A + (1.f-zA)*hhA;
        const float hnB = zB*hold3B + (1.f-zB)*hhB;
        hold3A = hnA; hold3B = hnB;
        if (!role) {
          s_h3[s3][g][0] = hnA; s_h3[s3][g][1] = hnB;
          s_fl[(t3>>4)&3][t3&15][0][g] = hnA;
          s_fl[(t3>>4)&3][t3&15][1][g] = hnB;
        }
      }
      PUBLISH(3, j);
    }
  }
  __syncthreads();

  // ---------------- attention epilogue (hT = s_h3[7]) ----------------
  for (int kk = tid; kk < 1024; kk += 256) e_w1[kk] = w1m[kk];
  if (tid < 32) { e_b1[tid] = b1[tid]; e_v[tid] = vv[tid]; }
  if (tid >= 64 && tid < 128) {
    const int u = tid & 31, bb = (tid - 64) >> 5;
    float s = b2[u];
    #pragma unroll
    for (int j = 0; j < 32; ++j) s += s_h3[7][j][bb] * w2m[j*32 + u];
    e_hw2[bb*32 + u] = s;
  }
  __syncthreads();

  #pragma unroll
  for (int c = 0; c < 4; ++c) {   // scores: 1024 tasks (2 batches x 512 t)
    const int idx = c*256 + tid;
    const int bb = idx >> 9, t2 = idx & 511;
    const float* row = obuf + ((size_t)(bb0+bb)*TLEN + t2)*32;
    float rr[32];
    #pragma unroll
    for (int j = 0; j < 32; j += 4) {
      const float4 r4 = *(const float4*)&row[j];
      rr[j]=r4.x; rr[j+1]=r4.y; rr[j+2]=r4.z; rr[j+3]=r4.w;
    }
    float sc = 0.f;
    for (int u = 0; u < 32; ++u) {
      float qv = e_b1[u] + e_hw2[bb*32 + u];
      #pragma unroll
      for (int j = 0; j < 32; ++j) qv += rr[j]*e_w1[j*32+u];
      sc += tanh_f(qv)*e_v[u];
    }
    e_sc[idx] = sc;    // bv dropped: constant shift cancels in softmax
  }
  __syncthreads();

  {  // softmax over T per batch: wave 0 -> b=0, wave 1 -> b=1
    if (wid < 2) {
      const int bb = wid;
      float sv[8]; float m = -1e30f;
      #pragma unroll
      for (int k = 0; k < 8; ++k) { sv[k] = e_sc[bb*512 + lane + 64*k]; m = fmaxf(m, sv[k]); }
      #pragma unroll
      for (int off = 32; off > 0; off >>= 1) m = fmaxf(m, __shfl_xor(m, off));
      float ss = 0.f;
      #pragma unroll
      for (int k = 0; k < 8; ++k) { sv[k] = __expf(sv[k]-m); ss += sv[k]; }
      #pragma unroll
      for (int off = 32; off > 0; off >>= 1) ss += __shfl_xor(ss, off);
      const float inv = 1.f/ss;
      #pragma unroll
      for (int k = 0; k < 8; ++k) e_sc[bb*512 + lane + 64*k] = sv[k]*inv;
    }
  }
  __syncthreads();

  if (tid < 64) {     // ctx = sum_t p_t * out_t (coalesced across u)
    const int u = tid & 31, bb = tid >> 5;
    float acc = 0.f;
    const float* orow = obuf + (size_t)(bb0+bb)*TLEN*32 + u;
    const float* prow = e_sc + bb*512;
    #pragma unroll 4
    for (int t2 = 0; t2 < 512; ++t2) acc += prow[t2]*orow[(size_t)t2*32];
    e_ctx[bb*32 + u] = acc;
  }
  __syncthreads();

  if (tid < 2) {      // final 2-class softmax
    const int bb = tid;
    float l0 = bd[0], l1 = bd[1];
    #pragma unroll
    for (int u = 0; u < 32; ++u) {
      const float cv = e_ctx[bb*32 + u];
      l0 += cv*wd[u*2]; l1 += cv*wd[u*2+1];
    }
    const float mm = fmaxf(l0, l1);
    const float ex0 = __expf(l0-mm), ex1 = __expf(l1-mm);
    const float den = ex0 + ex1;
    out[(bb0+bb)*2 + 0] = ex0/den;
    out[(bb0+bb)*2 + 1] = ex1/den;
  }
#undef WAITGE
#undef WAITGE2
#undef PUBLISH
}

extern "C" void kernel_launch(void* const* d_in, const int* in_sizes, int n_in,
                              void* d_out, int out_size, void* d_ws, size_t ws_size,
                              hipStream_t stream) {
  const float* x   = (const float*)d_in[0];
  const float* emb = (const float*)d_in[1];
  const float* k0  = (const float*)d_in[2];
  const float* r0  = (const float*)d_in[3];
  const float* bi0 = (const float*)d_in[4];
  const float* bh0 = (const float*)d_in[5];
  const float* k1  = (const float*)d_in[6];
  const float* r1  = (const float*)d_in[7];
  const float* bi1 = (const float*)d_in[8];
  const float* bh1 = (const float*)d_in[9];
  const float* k2  = (const float*)d_in[10];
  const float* r2  = (const float*)d_in[11];
  const float* bi2 = (const float*)d_in[12];
  const float* bh2 = (const float*)d_in[13];
  const float* k3  = (const float*)d_in[14];
  const float* r3  = (const float*)d_in[15];
  const float* bi3 = (const float*)d_in[16];
  const float* bh3 = (const float*)d_in[17];
  const float* w1  = (const float*)d_in[18];
  const float* b1  = (const float*)d_in[19];
  const float* w2  = (const float*)d_in[20];
  const float* b2  = (const float*)d_in[21];
  const float* v   = (const float*)d_in[22];
  const float* bv  = (const float*)d_in[23];
  const float* wd  = (const float*)d_in[24];
  const float* bd  = (const float*)d_in[25];

  float* out  = (float*)d_out;
  float* obuf = (float*)d_ws;   // 512*512*32*4 = 33.5 MB

  rnn_flow<<<dim3(256), dim3(256), 0, stream>>>(
      x, emb, k0, r0, bi0, bh0, k1, r1, bi1, bh1,
      k2, r2, bi2, bh2, k3, r3, bi3, bh3,
      w1, b1, w2, b2, v, bv, wd, bd, out, obuf);
}

// Round 8
// 1008.586 us; speedup vs baseline: 1.4929x; 1.4929x over previous
//
#include <hip/hip_runtime.h>

#define TLEN 512
#define FIN 16

__device__ __forceinline__ float sigm(float x) { return 1.0f / (1.0f + __expf(-x)); }
__device__ __forceinline__ float tanh_f(float x) {
  x = fminf(fmaxf(x, -15.0f), 15.0f);
  float e = __expf(2.0f * x);
  return (e - 1.0f) / (e + 1.0f);
}

// Pair-sum via DPP quad_perm [1,0,3,2] (lane ^= 1): pure VALU, no LDS pipe.
// Both lanes of a pair get the identical total (same two floats added).
__device__ __forceinline__ float dpp_pairsum(float x) {
  const int v = __builtin_amdgcn_update_dpp(0, __float_as_int(x),
                                            0xB1, 0xF, 0xF, true);
  return x + __int_as_float(v);
}

// R8: LDS-instruction-minimized pipeline. Diagnosis R3..R7: ~360 LDS instrs
// per interval on the shared CU LDS pipe (~8-12cyc each) = the ~5.3K-cycle
// interval; shfl_xor (ds_swizzle) and duplicate h reads were the bulk.
// Changes vs R3: (a) role splits the K-dim, each lane holds all 3 gate
// columns for its half (h read ONCE per wave, 2-group b128 broadcast);
// (b) cross-lane combine via DPP (VALU) not shfl (LDS); (c) own-unit h in
// a register. Skew/rings/staging identical to the verified R3/R4.
//   w0: L0 u0-31 (t=i) + L3A batch A (t=i-3)
//   w1: L0 u32-63 (t=i) + L3A batch B + chunk flush
//   w2: L1 (t=i-1)
//   w3: L2 (t=i-2) + L3 final (t=i-4)
__global__ __launch_bounds__(256, 1)
void rnn_dpp(const float* __restrict__ x, const float* __restrict__ emb,
             const float* __restrict__ k0, const float* __restrict__ r0,
             const float* __restrict__ bi0, const float* __restrict__ bh0,
             const float* __restrict__ k1, const float* __restrict__ r1,
             const float* __restrict__ bi1, const float* __restrict__ bh1,
             const float* __restrict__ k2, const float* __restrict__ r2,
             const float* __restrict__ bi2, const float* __restrict__ bh2,
             const float* __restrict__ k3, const float* __restrict__ r3,
             const float* __restrict__ bi3, const float* __restrict__ bh3,
             const float* __restrict__ w1m, const float* __restrict__ b1,
             const float* __restrict__ w2m, const float* __restrict__ b2,
             const float* __restrict__ vv, const float* __restrict__ bv,
             const float* __restrict__ wd, const float* __restrict__ bd,
             float* __restrict__ out, float* __restrict__ obuf)
{
  __shared__ __align__(16) float s_xin[TLEN][20][2];   // 80 KB [t][row][batch]
  __shared__ __align__(16) float s_h0[2][64][2];       // [slot][unit][batch]
  __shared__ __align__(16) float s_h1[2][32][2];
  __shared__ __align__(16) float s_h2[2][32][2];
  __shared__ __align__(16) float s_h3[2][32][2];
  __shared__ __align__(16) float s_pA[2][3][32][2];    // [par][gate][unit][batch]
  __shared__ __align__(16) float s_fl[2][16][2][32];   // flush ring [par][dt][b][u]
  // epilogue
  __shared__ __align__(16) float e_w1[1024];
  __shared__ __align__(16) float e_sc[1024];
  __shared__ float e_hw2[64], e_b1[32], e_v[32], e_ctx[64];

  const int tid  = threadIdx.x;
  const int wid  = tid >> 6;
  const int lane = tid & 63;
  const int g    = lane >> 1;
  const int rho  = lane & 1;      // K-split role
  const int bb0  = blockIdx.x * 2;

  float W[174];
  float bz = 0.f, br = 0.f, bxh = 0.f, bhh = 0.f;   // primary layer biases
  float cz = 0.f, cr = 0.f, cxh = 0.f, chh = 0.f;   // w3's L3 biases

  // ---------------- weight loading (K-half per lane, all 3 gates) --------
  if (wid <= 1) {                 // L0 unit u; + L3A unit g (own batch = wid)
    const int u = wid * 32 + g;
    #pragma unroll
    for (int q = 0; q < 3; ++q)
      #pragma unroll
      for (int j = 0; j < 10; ++j) {
        const int row = rho * 10 + j;
        W[q*10 + j] = (row < 19) ? k0[row*192 + q*64 + u] : 0.f;
      }
    #pragma unroll
    for (int q = 0; q < 3; ++q)
      #pragma unroll
      for (int j = 0; j < 32; ++j)
        W[30 + q*32 + j] = r0[(rho*32 + j)*192 + q*64 + u];
    #pragma unroll
    for (int q = 0; q < 3; ++q)
      #pragma unroll
      for (int j = 0; j < 16; ++j)
        W[126 + q*16 + j] = k3[(rho*16 + j)*96 + q*32 + g];
    bz = bi0[u] + bh0[u]; br = bi0[64+u] + bh0[64+u];
    bxh = bi0[128+u]; bhh = bh0[128+u];
  } else if (wid == 2) {          // L1 unit g
    const int u = g;
    #pragma unroll
    for (int q = 0; q < 3; ++q)
      #pragma unroll
      for (int j = 0; j < 32; ++j)
        W[q*32 + j] = k1[(rho*32 + j)*96 + q*32 + u];
    #pragma unroll
    for (int q = 0; q < 3; ++q)
      #pragma unroll
      for (int j = 0; j < 16; ++j)
        W[96 + q*16 + j] = r1[(rho*16 + j)*96 + q*32 + u];
    bz = bi1[u] + bh1[u]; br = bi1[32+u] + bh1[32+u];
    bxh = bi1[64+u]; bhh = bh1[64+u];
  } else {                        // L2 + L3-final, unit g
    const int u = g;
    #pragma unroll
    for (int q = 0; q < 3; ++q)
      #pragma unroll
      for (int j = 0; j < 16; ++j) {
        W[q*16 + j]      = k2[(rho*16 + j)*96 + q*32 + u];
        W[48 + q*16 + j] = r2[(rho*16 + j)*96 + q*32 + u];
        W[96 + q*16 + j] = r3[(rho*16 + j)*96 + q*32 + u];
      }
    bz = bi2[u] + bh2[u]; br = bi2[32+u] + bh2[32+u];
    bxh = bi2[64+u]; bhh = bh2[64+u];
    cz = bi3[u] + bh3[u]; cr = bi3[32+u] + bh3[32+u];
    cxh = bi3[64+u]; chh = bh3[64+u];
  }

  // ---------------- zero rings ----------------
  ((float*)s_h0)[tid] = 0.f;                       // 256 floats
  if (tid < 128) {
    ((float*)s_h1)[tid] = 0.f;
    ((float*)s_h2)[tid] = 0.f;
    ((float*)s_h3)[tid] = 0.f;
  }

  // ---------------- stage full input into LDS (R4-verified) ----------------
  for (int r = tid; r < 2*TLEN; r += 256) {
    const int b2 = r & 1, t2 = r >> 1;
    const float* xr = &x[((size_t)(bb0 + b2) * TLEN + t2) * FIN];
    const float4 x0 = *(const float4*)(xr);
    const float4 x1 = *(const float4*)(xr + 4);
    const float4 x2 = *(const float4*)(xr + 8);
    const float4 x3 = *(const float4*)(xr + 12);
    float v[20];
    v[0]=x0.x; v[1]=x0.z; v[2]=x0.w;
    v[3]=x1.x; v[4]=x1.y; v[5]=x1.z; v[6]=x1.w;
    v[7]=x2.x; v[8]=x2.y; v[9]=x2.z; v[10]=x2.w;
    v[11]=x3.x; v[12]=x3.y; v[13]=x3.z; v[14]=x3.w;
    const int id = (int)x0.y;
    const float4 e4 = *(const float4*)&emb[id*4];
    v[15]=e4.x; v[16]=e4.y; v[17]=e4.z; v[18]=e4.w; v[19]=0.f;
    #pragma unroll
    for (int j = 0; j < 20; ++j) s_xin[t2][j][b2] = v[j];
  }

  // w1's chunk flush (16 steps x 2 batches x 32 units)
  auto flush = [&](int c) {
    const int par = c & 1;
    #pragma unroll
    for (int it = 0; it < 4; ++it) {
      const int f4 = it*64 + lane;
      const int u4 = f4 & 7, row = f4 >> 3;
      const int dt = row >> 1, b2 = row & 1;
      const float4 vq = *(const float4*)&s_fl[par][dt][b2][u4*4];
      *(float4*)&obuf[(((size_t)(bb0+b2)*TLEN) + c*16 + dt)*32 + u4*4] = vq;
    }
  };

  float hold0A = 0.f, hold0B = 0.f;   // per-wave recurrent registers
  float hold1A = 0.f, hold1B = 0.f;
  float hold2A = 0.f, hold2B = 0.f, hold3A = 0.f, hold3B = 0.f;

  // ---------------- pipelined recurrence: 516 intervals ----------------
  for (int i = 0; i < 516; ++i) {
    __syncthreads();

    if (wid <= 1) {
      // ---- L0, t = i
      if (i < 512) {
        const int t = i;
        const int ps = (t - 1) & 1, ws = t & 1;
        const int u = wid*32 + g;
        float zA=0.f,zB=0.f,rA=0.f,rB=0.f,xhA=0.f,xhB=0.f,hpA=0.f,hpB=0.f;
        const float* xb = &s_xin[t][rho*10][0];
        #pragma unroll
        for (int j4 = 0; j4 < 5; ++j4) {              // x-part (rows 2j4,2j4+1)
          const float4 q = *(const float4*)(xb + j4*4);
          const int j0 = 2*j4, j1 = j0 + 1;
          zA  += W[j0]*q.x;    zB  += W[j0]*q.y;    zA  += W[j1]*q.z;    zB  += W[j1]*q.w;
          rA  += W[10+j0]*q.x; rB  += W[10+j0]*q.y; rA  += W[10+j1]*q.z; rB  += W[10+j1]*q.w;
          xhA += W[20+j0]*q.x; xhB += W[20+j0]*q.y; xhA += W[20+j1]*q.z; xhB += W[20+j1]*q.w;
        }
        const float* hb = &s_h0[ps][rho*32][0];
        #pragma unroll
        for (int j4 = 0; j4 < 16; ++j4) {             // h-part
          const float4 q = *(const float4*)(hb + j4*4);
          const int j0 = 2*j4, j1 = j0 + 1;
          zA += W[30+j0]*q.x; zB += W[30+j0]*q.y; zA += W[30+j1]*q.z; zB += W[30+j1]*q.w;
          rA += W[62+j0]*q.x; rB += W[62+j0]*q.y; rA += W[62+j1]*q.z; rB += W[62+j1]*q.w;
          hpA += W[94+j0]*q.x; hpB += W[94+j0]*q.y; hpA += W[94+j1]*q.z; hpB += W[94+j1]*q.w;
        }
        const float mzA = dpp_pairsum(zA) + bz,  mzB = dpp_pairsum(zB) + bz;
        const float mrA = dpp_pairsum(rA) + br,  mrB = dpp_pairsum(rB) + br;
        const float sxA = dpp_pairsum(xhA) + bxh, sxB = dpp_pairsum(xhB) + bxh;
        const float spA = dpp_pairsum(hpA) + bhh, spB = dpp_pairsum(hpB) + bhh;
        const float z0A = sigm(mzA), r0A = sigm(mrA);
        const float z0B = sigm(mzB), r0B = sigm(mrB);
        const float hhA = tanh_f(sxA + r0A*spA);
        const float hhB = tanh_f(sxB + r0B*spB);
        hold0A = z0A*hold0A + (1.f - z0A)*hhA;
        hold0B = z0B*hold0B + (1.f - z0B)*hhB;
        if (!rho) *(float2*)&s_h0[ws][u][0] = make_float2(hold0A, hold0B);
      }
      // ---- L3A (k3 . h2[t-3]), own batch = wid
      if (i >= 3 && i <= 514) {
        const int t3a = i - 3;
        const int sl2 = t3a & 1;
        float pz=0.f, pr=0.f, ph=0.f;
        const float* hb = &s_h2[sl2][rho*16][0];
        #pragma unroll
        for (int j4 = 0; j4 < 8; ++j4) {
          const float4 q = *(const float4*)(hb + j4*4);
          const float hx = (wid == 0) ? q.x : q.y;    // unit 2j4
          const float hz = (wid == 0) ? q.z : q.w;    // unit 2j4+1
          const int j0 = 2*j4, j1 = j0 + 1;
          pz += W[126+j0]*hx + W[126+j1]*hz;
          pr += W[142+j0]*hx + W[142+j1]*hz;
          ph += W[158+j0]*hx + W[158+j1]*hz;
        }
        const float tz = dpp_pairsum(pz);
        const float tr = dpp_pairsum(pr);
        const float th = dpp_pairsum(ph);
        if (!rho) {
          s_pA[t3a & 1][0][g][wid] = tz;
          s_pA[t3a & 1][1][g][wid] = tr;
          s_pA[t3a & 1][2][g][wid] = th;
        }
      }
      // ---- w1: chunk flush
      if (wid == 1 && i >= 20 && ((i - 20) & 15) == 0) flush((i - 20) >> 4);
    } else if (wid == 2) {
      // ---- L1, t = i-1
      if (i >= 1 && i <= 512) {
        const int t = i - 1;
        const int ws = t & 1, ps = (t - 1) & 1;
        float zA=0.f,zB=0.f,rA=0.f,rB=0.f,xhA=0.f,xhB=0.f,hpA=0.f,hpB=0.f;
        const float* hb0 = &s_h0[ws][rho*32][0];      // h0[t]
        #pragma unroll
        for (int j4 = 0; j4 < 16; ++j4) {
          const float4 q = *(const float4*)(hb0 + j4*4);
          const int j0 = 2*j4, j1 = j0 + 1;
          zA += W[j0]*q.x; zB += W[j0]*q.y; zA += W[j1]*q.z; zB += W[j1]*q.w;
          rA += W[32+j0]*q.x; rB += W[32+j0]*q.y; rA += W[32+j1]*q.z; rB += W[32+j1]*q.w;
          xhA += W[64+j0]*q.x; xhB += W[64+j0]*q.y; xhA += W[64+j1]*q.z; xhB += W[64+j1]*q.w;
        }
        const float* hb1 = &s_h1[ps][rho*16][0];      // h1[t-1]
        #pragma unroll
        for (int j4 = 0; j4 < 8; ++j4) {
          const float4 q = *(const float4*)(hb1 + j4*4);
          const int j0 = 2*j4, j1 = j0 + 1;
          zA += W[96+j0]*q.x; zB += W[96+j0]*q.y; zA += W[96+j1]*q.z; zB += W[96+j1]*q.w;
          rA += W[112+j0]*q.x; rB += W[112+j0]*q.y; rA += W[112+j1]*q.z; rB += W[112+j1]*q.w;
          hpA += W[128+j0]*q.x; hpB += W[128+j0]*q.y; hpA += W[128+j1]*q.z; hpB += W[128+j1]*q.w;
        }
        const float mzA = dpp_pairsum(zA) + bz,  mzB = dpp_pairsum(zB) + bz;
        const float mrA = dpp_pairsum(rA) + br,  mrB = dpp_pairsum(rB) + br;
        const float sxA = dpp_pairsum(xhA) + bxh, sxB = dpp_pairsum(xhB) + bxh;
        const float spA = dpp_pairsum(hpA) + bhh, spB = dpp_pairsum(hpB) + bhh;
        const float z1A = sigm(mzA), r1A = sigm(mrA);
        const float z1B = sigm(mzB), r1B = sigm(mrB);
        const float hhA = tanh_f(sxA + r1A*spA);
        const float hhB = tanh_f(sxB + r1B*spB);
        hold1A = z1A*hold1A + (1.f - z1A)*hhA;
        hold1B = z1B*hold1B + (1.f - z1B)*hhB;
        if (!rho) *(float2*)&s_h1[ws][g][0] = make_float2(hold1A, hold1B);
      }
    } else {
      // ---- L2, t = i-2
      if (i >= 2 && i <= 513) {
        const int t = i - 2;
        const int ws = t & 1, ps = (t - 1) & 1;
        float zA=0.f,zB=0.f,rA=0.f,rB=0.f,xhA=0.f,xhB=0.f,hpA=0.f,hpB=0.f;
        const float* hb1 = &s_h1[ws][rho*16][0];      // h1[t]
        #pragma unroll
        for (int j4 = 0; j4 < 8; ++j4) {
          const float4 q = *(const float4*)(hb1 + j4*4);
          const int j0 = 2*j4, j1 = j0 + 1;
          zA += W[j0]*q.x; zB += W[j0]*q.y; zA += W[j1]*q.z; zB += W[j1]*q.w;
          rA += W[16+j0]*q.x; rB += W[16+j0]*q.y; rA += W[16+j1]*q.z; rB += W[16+j1]*q.w;
          xhA += W[32+j0]*q.x; xhB += W[32+j0]*q.y; xhA += W[32+j1]*q.z; xhB += W[32+j1]*q.w;
        }
        const float* hb2 = &s_h2[ps][rho*16][0];      // h2[t-1]
        #pragma unroll
        for (int j4 = 0; j4 < 8; ++j4) {
          const float4 q = *(const float4*)(hb2 + j4*4);
          const int j0 = 2*j4, j1 = j0 + 1;
          zA += W[48+j0]*q.x; zB += W[48+j0]*q.y; zA += W[48+j1]*q.z; zB += W[48+j1]*q.w;
          rA += W[64+j0]*q.x; rB += W[64+j0]*q.y; rA += W[64+j1]*q.z; rB += W[64+j1]*q.w;
          hpA += W[80+j0]*q.x; hpB += W[80+j0]*q.y; hpA += W[80+j1]*q.z; hpB += W[80+j1]*q.w;
        }
        const float mzA = dpp_pairsum(zA) + bz,  mzB = dpp_pairsum(zB) + bz;
        const float mrA = dpp_pairsum(rA) + br,  mrB = dpp_pairsum(rB) + br;
        const float sxA = dpp_pairsum(xhA) + bxh, sxB = dpp_pairsum(xhB) + bxh;
        const float spA = dpp_pairsum(hpA) + bhh, spB = dpp_pairsum(hpB) + bhh;
        const float z2A = sigm(mzA), r2A = sigm(mrA);
        const float z2B = sigm(mzB), r2B = sigm(mrB);
        const float hhA = tanh_f(sxA + r2A*spA);
        const float hhB = tanh_f(sxB + r2B*spB);
        hold2A = z2A*hold2A + (1.f - z2A)*hhA;
        hold2B = z2B*hold2B + (1.f - z2B)*hhB;
        if (!rho) *(float2*)&s_h2[ws][g][0] = make_float2(hold2A, hold2B);
      }
      // ---- L3 final, t = i-4
      if (i >= 4) {
        const int t3 = i - 4;
        const int ws = t3 & 1, ps = (t3 - 1) & 1;
        float zA=0.f,zB=0.f,rA=0.f,rB=0.f,hpA=0.f,hpB=0.f;
        const float* hb3 = &s_h3[ps][rho*16][0];      // h3[t3-1]
        #pragma unroll
        for (int j4 = 0; j4 < 8; ++j4) {
          const float4 q = *(const float4*)(hb3 + j4*4);
          const int j0 = 2*j4, j1 = j0 + 1;
          zA += W[96+j0]*q.x; zB += W[96+j0]*q.y; zA += W[96+j1]*q.z; zB += W[96+j1]*q.w;
          rA += W[112+j0]*q.x; rB += W[112+j0]*q.y; rA += W[112+j1]*q.z; rB += W[112+j1]*q.w;
          hpA += W[128+j0]*q.x; hpB += W[128+j0]*q.y; hpA += W[128+j1]*q.z; hpB += W[128+j1]*q.w;
        }
        const float2 paz = *(const float2*)&s_pA[t3 & 1][0][g][0];
        const float2 par = *(const float2*)&s_pA[t3 & 1][1][g][0];
        const float2 pah = *(const float2*)&s_pA[t3 & 1][2][g][0];
        const float mzA = paz.x + dpp_pairsum(zA) + cz;
        const float mzB = paz.y + dpp_pairsum(zB) + cz;
        const float mrA = par.x + dpp_pairsum(rA) + cr;
        const float mrB = par.y + dpp_pairsum(rB) + cr;
        const float sxA = pah.x + cxh, sxB = pah.y + cxh;
        const float spA = dpp_pairsum(hpA) + chh;
        const float spB = dpp_pairsum(hpB) + chh;
        const float z3A = sigm(mzA), r3A = sigm(mrA);
        const float z3B = sigm(mzB), r3B = sigm(mrB);
        const float hhA = tanh_f(sxA + r3A*spA);
        const float hhB = tanh_f(sxB + r3B*spB);
        hold3A = z3A*hold3A + (1.f - z3A)*hhA;
        hold3B = z3B*hold3B + (1.f - z3B)*hhB;
        if (!rho) {
          *(float2*)&s_h3[ws][g][0] = make_float2(hold3A, hold3B);
          s_fl[(t3>>4)&1][t3&15][0][g] = hold3A;
          s_fl[(t3>>4)&1][t3&15][1][g] = hold3B;
        }
      }
    }
  }
  __syncthreads();

  // ---------------- tail flush (chunk 31) + attention epilogue -------------
  if (wid == 1) flush(31);

  for (int kk = tid; kk < 1024; kk += 256) e_w1[kk] = w1m[kk];
  if (tid < 32) { e_b1[tid] = b1[tid]; e_v[tid] = vv[tid]; }
  if (tid >= 64 && tid < 128) {
    const int u = tid & 31, bb = (tid - 64) >> 5;
    float s = b2[u];
    #pragma unroll
    for (int j = 0; j < 32; ++j) s += s_h3[1][j][bb] * w2m[j*32 + u];
    e_hw2[bb*32 + u] = s;
  }
  __syncthreads();

  #pragma unroll
  for (int c = 0; c < 4; ++c) {   // scores: 1024 tasks (2 batches x 512 t)
    const int idx = c*256 + tid;
    const int bb = idx >> 9, t2 = idx & 511;
    const float* row = obuf + ((size_t)(bb0+bb)*TLEN + t2)*32;
    float rr[32];
    #pragma unroll
    for (int j = 0; j < 32; j += 4) {
      const float4 r4 = *(const float4*)&row[j];
      rr[j]=r4.x; rr[j+1]=r4.y; rr[j+2]=r4.z; rr[j+3]=r4.w;
    }
    float sc = 0.f;
    for (int u = 0; u < 32; ++u) {
      float qv = e_b1[u] + e_hw2[bb*32 + u];
      #pragma unroll
      for (int j = 0; j < 32; ++j) qv += rr[j]*e_w1[j*32+u];
      sc += tanh_f(qv)*e_v[u];
    }
    e_sc[idx] = sc;    // bv dropped: constant shift cancels in softmax
  }
  __syncthreads();

  {  // softmax over T per batch: wave 0 -> b=0, wave 1 -> b=1
    if (wid < 2) {
      const int bb = wid;
      float sv[8]; float m = -1e30f;
      #pragma unroll
      for (int k = 0; k < 8; ++k) { sv[k] = e_sc[bb*512 + lane + 64*k]; m = fmaxf(m, sv[k]); }
      #pragma unroll
      for (int off = 32; off > 0; off >>= 1) m = fmaxf(m, __shfl_xor(m, off));
      float ss = 0.f;
      #pragma unroll
      for (int k = 0; k < 8; ++k) { sv[k] = __expf(sv[k]-m); ss += sv[k]; }
      #pragma unroll
      for (int off = 32; off > 0; off >>= 1) ss += __shfl_xor(ss, off);
      const float inv = 1.f/ss;
      #pragma unroll
      for (int k = 0; k < 8; ++k) e_sc[bb*512 + lane + 64*k] = sv[k]*inv;
    }
  }
  __syncthreads();

  if (tid < 64) {     // ctx = sum_t p_t * out_t (coalesced across u)
    const int u = tid & 31, bb = tid >> 5;
    float acc = 0.f;
    const float* orow = obuf + (size_t)(bb0+bb)*TLEN*32 + u;
    const float* prow = e_sc + bb*512;
    #pragma unroll 4
    for (int t2 = 0; t2 < 512; ++t2) acc += prow[t2]*orow[(size_t)t2*32];
    e_ctx[bb*32 + u] = acc;
  }
  __syncthreads();

  if (tid < 2) {      // final 2-class softmax
    const int bb = tid;
    float l0 = bd[0], l1 = bd[1];
    #pragma unroll
    for (int u = 0; u < 32; ++u) {
      const float cv = e_ctx[bb*32 + u];
      l0 += cv*wd[u*2]; l1 += cv*wd[u*2+1];
    }
    const float mm = fmaxf(l0, l1);
    const float ex0 = __expf(l0-mm), ex1 = __expf(l1-mm);
    const float den = ex0 + ex1;
    out[(bb0+bb)*2 + 0] = ex0/den;
    out[(bb0+bb)*2 + 1] = ex1/den;
  }
}

extern "C" void kernel_launch(void* const* d_in, const int* in_sizes, int n_in,
                              void* d_out, int out_size, void* d_ws, size_t ws_size,
                              hipStream_t stream) {
  const float* x   = (const float*)d_in[0];
  const float* emb = (const float*)d_in[1];
  const float* k0  = (const float*)d_in[2];
  const float* r0  = (const float*)d_in[3];
  const float* bi0 = (const float*)d_in[4];
  const float* bh0 = (const float*)d_in[5];
  const float* k1  = (const float*)d_in[6];
  const float* r1  = (const float*)d_in[7];
  const float* bi1 = (const float*)d_in[8];
  const float* bh1 = (const float*)d_in[9];
  const float* k2  = (const float*)d_in[10];
  const float* r2  = (const float*)d_in[11];
  const float* bi2 = (const float*)d_in[12];
  const float* bh2 = (const float*)d_in[13];
  const float* k3  = (const float*)d_in[14];
  const float* r3  = (const float*)d_in[15];
  const float* bi3 = (const float*)d_in[16];
  const float* bh3 = (const float*)d_in[17];
  const float* w1  = (const float*)d_in[18];
  const float* b1  = (const float*)d_in[19];
  const float* w2  = (const float*)d_in[20];
  const float* b2  = (const float*)d_in[21];
  const float* v   = (const float*)d_in[22];
  const float* bv  = (const float*)d_in[23];
  const float* wd  = (const float*)d_in[24];
  const float* bd  = (const float*)d_in[25];

  float* out  = (float*)d_out;
  float* obuf = (float*)d_ws;   // 512*512*32*4 = 33.5 MB

  rnn_dpp<<<dim3(256), dim3(256), 0, stream>>>(
      x, emb, k0, r0, bi0, bh0, k1, r1, bi1, bh1,
      k2, r2, bi2, bh2, k3, r3, bi3, bh3,
      w1, b1, w2, b2, v, bv, wd, bd, out, obuf);
}